// Round 2
// 275.863 us; speedup vs baseline: 1.2814x; 1.2814x over previous
//
#include <hip/hip_runtime.h>
#include <hip/hip_bf16.h>

// KroneckerMixer: B=64, N=1024, K=64, BASIS=8, T=0.2, 20 sinkhorn iters.
// R8 pipeline (bf16 path, ws >= 40.25 MB):
//   k_front : fused, grid EXACTLY 256 blocks (1 block/CU at ~120 VGPR -> all
//             barrier participants co-resident regardless of dispatch order).
//     Blocks 0..15  = A-sinkhorn u/v solver, E HELD IN REGISTERS:
//       prologue loads L rows (4/wave), computes e=exp(L/T) into e[4][16]
//       (64 VGPR/thread), emits Eh/El bf16 hi/lo (or E0 fp32 fallback).
//       Per iter: row sums vs v (regs), DPP reduce + readlane -> u;
//       col partials from regs vs u; cross-wave LDS tree (16->8->colsum);
//       post per-block partial (sc1) + FLAG-LINE barrier (monotonic per-block
//       iteration tags in one 64B line, single 16-lane poll load) + gather.
//       No E0 re-streaming, no serialized fetch_add chain.
//     Blocks 16..255 = W-path (R5-verified math): per-n 64x64 sinkhorn +
//       x_local matmul -> XL fp32 [n][c]. 1024 n's over 240 blocks:
//       first 64 blocks 5 n's, remaining 176 blocks 4 n's.
//   k_xt    : transpose + v-scale + hi/lo split XL -> XTh/XTl bf16 [c][n].
//   k_gemm3 : out[m][c] = u_m*(Eh*XTh + El*XTh + Eh*XTl) via mfma 16x16x32 bf16.
// Fallback (small ws): fp32 k_gemm reading E0 with u/v folded.

#define N_DIM 1024
#define INV_T 5.0f
#define NBAR 16  // A-sinkhorn barrier blocks

typedef __attribute__((ext_vector_type(8))) short short8;
typedef __attribute__((ext_vector_type(4))) float float4v;

// ---------------- wave64 sum reduction via DPP (VALU pipe) -------------------
// Result valid in lane 63.
__device__ __forceinline__ float wave_red_sum(float x) {
#define DPP_ADD(C)                                                            \
  {                                                                           \
    int _y = __builtin_amdgcn_update_dpp(0, __float_as_int(x), (C), 0xf, 0xf, \
                                         true);                               \
    x += __int_as_float(_y);                                                  \
  }
  DPP_ADD(0x111);
  DPP_ADD(0x112);
  DPP_ADD(0x114);
  DPP_ADD(0x118);
  DPP_ADD(0x142);
  DPP_ADD(0x143);
#undef DPP_ADD
  return x;
}

// ---------------- kernel 1: fused sinkA(u,v) + wpath -------------------------
// grid 256 x 1024.
__global__ __launch_bounds__(1024) void k_front(
    const float* __restrict__ x, const float* __restrict__ L,
    const float* __restrict__ W1, const float* __restrict__ WV,
    float* __restrict__ E0, __hip_bfloat16* __restrict__ Eh,
    __hip_bfloat16* __restrict__ El, float* __restrict__ P,
    unsigned* __restrict__ ctrl, float* __restrict__ u_g,
    float* __restrict__ v_g, float* __restrict__ XL, int write_bf16) {
  __shared__ __align__(16) float smem[9600];
  const int t = threadIdx.x;
  const int bid = blockIdx.x;
  const int lane = t & 63;
  const int w = t >> 6;  // 0..15

  if (bid < NBAR) {
    // =================== A-sinkhorn u/v role (E in registers) ===============
    float* v_s = smem;               // [1024]
    float* uS = smem + 1024;         // [64]
    float* red = smem + 1024 + 64;   // [8][1032] cross-wave reduce buffer
    const int b = bid;
    const int r0 = b * 64;
    unsigned* flags = ctrl;  // 16 words, one cache line, zeroed by memset

    // ---- prologue: rows 4w..4w+3, cols lane*16..+15 -> e[4][16] in VGPRs
    float e[4][16];
#pragma unroll
    for (int j = 0; j < 4; ++j) {
      const int r = r0 + 4 * w + j;
      const float4* Lr = (const float4*)(L + (size_t)r * N_DIM + lane * 16);
#pragma unroll
      for (int q = 0; q < 4; ++q) {
        float4 f = Lr[q];
        e[j][4 * q + 0] = __expf(f.x * INV_T);
        e[j][4 * q + 1] = __expf(f.y * INV_T);
        e[j][4 * q + 2] = __expf(f.z * INV_T);
        e[j][4 * q + 3] = __expf(f.w * INV_T);
      }
      const size_t off = (size_t)r * N_DIM + lane * 16;
      if (write_bf16) {
        __align__(16) ushort hb[16], lb[16];
#pragma unroll
        for (int q = 0; q < 16; ++q) {
          __hip_bfloat16 h = __float2bfloat16(e[j][q]);
          hb[q] = *(ushort*)&h;
          __hip_bfloat16 l2 = __float2bfloat16(e[j][q] - __bfloat162float(h));
          lb[q] = *(ushort*)&l2;
        }
        *(uint4*)&Eh[off] = *(uint4*)&hb[0];
        *(uint4*)&Eh[off + 8] = *(uint4*)&hb[8];
        *(uint4*)&El[off] = *(uint4*)&lb[0];
        *(uint4*)&El[off + 8] = *(uint4*)&lb[8];
      } else {
        float4* Er = (float4*)(E0 + off);
#pragma unroll
        for (int q = 0; q < 4; ++q) {
          float4 g;
          g.x = e[j][4 * q + 0];
          g.y = e[j][4 * q + 1];
          g.z = e[j][4 * q + 2];
          g.w = e[j][4 * q + 3];
          Er[q] = g;
        }
      }
    }
    v_s[t] = 1.0f;  // iter0 row pass sums raw e (v == 1)
    __syncthreads();

    float u[4];
    for (int it = 0; it < 20; ++it) {
      // ---- row pass from registers: u_i = 1/sum_c e[i][c]*v[c]
      float vv[16];
#pragma unroll
      for (int q = 0; q < 4; ++q)
        *(float4*)&vv[4 * q] = *(const float4*)&v_s[lane * 16 + 4 * q];
#pragma unroll
      for (int j = 0; j < 4; ++j) {
        float p = 0.f;
#pragma unroll
        for (int k = 0; k < 16; ++k) p += e[j][k] * vv[k];
        p = wave_red_sum(p);  // lane 63
        float ps =
            __int_as_float(__builtin_amdgcn_readlane(__float_as_int(p), 63));
        u[j] = 1.0f / ps;  // all lanes
      }
      // ---- col partials for this wave's 4 rows (cols lane*16+k)
      float cpl[16];
#pragma unroll
      for (int k = 0; k < 16; ++k)
        cpl[k] = e[0][k] * u[0] + e[1][k] * u[1] + e[2][k] * u[2] +
                 e[3][k] * u[3];
      // ---- cross-wave reduce: waves 8..15 store, waves 0..7 accumulate
      if (w >= 8) {
#pragma unroll
        for (int q = 0; q < 4; ++q)
          *(float4*)&red[(w - 8) * 1032 + lane * 16 + 4 * q] =
              *(float4*)&cpl[4 * q];
      }
      __syncthreads();
      if (w < 8) {
        float* rr = &red[w * 1032 + lane * 16];
#pragma unroll
        for (int q = 0; q < 4; ++q) {
          float4 rv = *(float4*)&rr[4 * q];
          rv.x += cpl[4 * q + 0];
          rv.y += cpl[4 * q + 1];
          rv.z += cpl[4 * q + 2];
          rv.w += cpl[4 * q + 3];
          *(float4*)&rr[4 * q] = rv;
        }
      }
      __syncthreads();
      // ---- block col sum (thread t = col t) -> post partial (sc1)
      float cp = 0.f;
#pragma unroll
      for (int ww = 0; ww < 8; ++ww) cp += red[ww * 1032 + t];
      float* Pw = P + (it & 1) * (NBAR * N_DIM);
      __hip_atomic_store(&Pw[b * N_DIM + t], cp, __ATOMIC_RELAXED,
                         __HIP_MEMORY_SCOPE_AGENT);
      if (it == 19 && lane == 0) {
#pragma unroll
        for (int j = 0; j < 4; ++j) uS[4 * w + j] = u[j];
      }
      __syncthreads();  // vmcnt(0) drain: partials globally visible
      // ---- flag-line barrier: post monotonic tag, poll all 16 in one load
      if (t == 0)
        __hip_atomic_store(&flags[b], (unsigned)(it + 1), __ATOMIC_RELAXED,
                           __HIP_MEMORY_SCOPE_AGENT);
      if (w == 0 && lane < NBAR) {
        while (__hip_atomic_load(&flags[lane], __ATOMIC_RELAXED,
                                 __HIP_MEMORY_SCOPE_AGENT) <
               (unsigned)(it + 1))
          __builtin_amdgcn_s_sleep(2);
      }
      __syncthreads();
      // ---- v update: gather 16 partials (sc1, coalesced)
      float s2 = 0.f;
#pragma unroll
      for (int pb = 0; pb < NBAR; ++pb)
        s2 += __hip_atomic_load(&Pw[pb * N_DIM + t], __ATOMIC_RELAXED,
                                __HIP_MEMORY_SCOPE_AGENT);
      v_s[t] = 1.0f / s2;
      __syncthreads();
    }
    // ---- epilogue: emit u (this block's 64 rows) and v (block 0)
    if (t < 64) u_g[r0 + t] = uS[t];
    if (b == 0) v_g[t] = v_s[t];
  } else {
    // =================== W-path role: 4 or 5 n's sequentially ==============
    float* uS2 = smem;                    // [64]
    float* ps = smem + 64;                // [16][64]
    float* Ws = smem + 64 + 1024;         // [64*64]
    float* Xs = smem + 64 + 1024 + 4096;  // [64*65]
    const int idx = bid - NBAR;  // 0..239
    // first 64 blocks: 5 n's from idx*5; remaining 176 blocks: 4 n's from
    // 320 + (idx-64)*4.  64*5 + 176*4 = 1024.
    const int cnt = (idx < 64) ? 5 : 4;
    const int base_n = (idx < 64) ? idx * 5 : 320 + (idx - 64) * 4;

    for (int s = 0; s < cnt; ++s) {
      const int n = base_n + s;
      float w1[8];
#pragma unroll
      for (int k = 0; k < 8; ++k) w1[k] = W1[n * 8 + k];

      // element j: (row i = j*16 + w, col o = lane)
      float ew[4];
#pragma unroll
      for (int j = 0; j < 4; ++j) {
        const int f = j * 1024 + t;
        float acc = 0.f;
#pragma unroll
        for (int k = 0; k < 8; ++k) acc += w1[k] * WV[k * 4096 + f];
        ew[j] = __expf(acc * INV_T);
      }

      float vt = 1.0f;
      for (int it = 0; it < 20; ++it) {
#pragma unroll
        for (int j = 0; j < 4; ++j) {
          float pp = wave_red_sum(ew[j] * vt);
          if (lane == 63) uS2[j * 16 + w] = 1.0f / pp;
        }
        // uS2[j*16+w] written & read by the same wave: in-order LDS pipe
        float cp = 0.f;
#pragma unroll
        for (int j = 0; j < 4; ++j) cp += ew[j] * uS2[j * 16 + w];
        ps[w * 64 + lane] = cp;
        __syncthreads();
        float sv = 0.f;
#pragma unroll
        for (int ww = 0; ww < 16; ++ww) sv += ps[ww * 64 + lane];
        vt = 1.0f / sv;
        __syncthreads();
      }

#pragma unroll
      for (int j = 0; j < 4; ++j)
        Ws[(j * 16 + w) * 64 + lane] = ew[j] * uS2[j * 16 + w] * vt;
#pragma unroll
      for (int j = 0; j < 4; ++j) {
        const int f = j * 1024 + t;  // batch bb = f>>6, col i = f&63
        Xs[(f >> 6) * 65 + (f & 63)] =
            x[(size_t)(f >> 6) * 65536 + n * 64 + (f & 63)];
      }
      __syncthreads();

      // x_local[bb][o] = sum_i Xs[bb][i] * Ws[i][o]; thread = (bb, 4 o's)
      const int bb = t >> 4;
      const int o4 = (t & 15) * 4;
      float4 a4 = {0.f, 0.f, 0.f, 0.f};
#pragma unroll 4
      for (int i = 0; i < 64; ++i) {
        float4 w4 = *(const float4*)&Ws[i * 64 + o4];
        float xv = Xs[bb * 65 + i];
        a4.x += xv * w4.x;
        a4.y += xv * w4.y;
        a4.z += xv * w4.z;
        a4.w += xv * w4.w;
      }
      *(float4*)&XL[(size_t)n * 4096 + bb * 64 + o4] = a4;
      __syncthreads();  // before next n reuses LDS
    }
  }
}

// ---------------- kernel 2b: transpose + v-scale + hi/lo split ---------------
// XTh/XTl[c][n] = hi/lo bf16 of (v[n] * XL[n][c]).
__global__ __launch_bounds__(256) void k_xt(const float* __restrict__ XL,
                                            const float* __restrict__ v_g,
                                            __hip_bfloat16* __restrict__ XTh,
                                            __hip_bfloat16* __restrict__ XTl) {
  __shared__ float T[64 * 68];
  __shared__ float vsh[64];
  const int t = threadIdx.x;
  const int n0 = blockIdx.x * 64;
  const int c0 = blockIdx.y * 64;
  if (t < 64) vsh[t] = v_g[n0 + t];
  {
    const int r = t >> 4;         // 0..15
    const int c4 = (t & 15) * 4;  // 0..60
#pragma unroll
    for (int p = 0; p < 4; ++p) {
      float4 f =
          *(const float4*)&XL[(size_t)(n0 + r + 16 * p) * 4096 + c0 + c4];
      *(float4*)&T[(r + 16 * p) * 68 + c4] = f;
    }
  }
  __syncthreads();
  const int cl = t >> 2;        // 0..63
  const int nb = (t & 3) * 16;  // 0,16,32,48
  __align__(16) __hip_bfloat16 hbuf[16];
  __align__(16) __hip_bfloat16 lbuf[16];
#pragma unroll
  for (int j = 0; j < 16; ++j) {
    float xv = T[(nb + j) * 68 + cl] * vsh[nb + j];
    __hip_bfloat16 h = __float2bfloat16(xv);
    hbuf[j] = h;
    lbuf[j] = __float2bfloat16(xv - __bfloat162float(h));
  }
  const size_t off = (size_t)(c0 + cl) * 1024 + n0 + nb;
  *(uint4*)&XTh[off] = *(uint4*)&hbuf[0];
  *(uint4*)&XTh[off + 8] = *(uint4*)&hbuf[8];
  *(uint4*)&XTl[off] = *(uint4*)&lbuf[0];
  *(uint4*)&XTl[off + 8] = *(uint4*)&lbuf[8];
}

// ---------------- kernel 3 (bf16): out = u ⊙ (Eh*XTh + El*XTh + Eh*XTl) ------
// D[m=1024][c=4096], 128x128 block tile, 4 waves each 64x64 of 16x16x32 MFMA.
#define LSTR 72  // padded LDS row stride (elements)
__global__ __launch_bounds__(256) void k_gemm3(
    const ushort* __restrict__ Eh, const ushort* __restrict__ El,
    const ushort* __restrict__ XTh, const ushort* __restrict__ XTl,
    const float* __restrict__ u_g, float* __restrict__ out) {
  __shared__ ushort As[128 * LSTR];
  __shared__ ushort Xs[128 * LSTR];
  __shared__ float ush[128];
  const int t = threadIdx.x;
  const int m0 = blockIdx.x * 128;
  const int c0 = blockIdx.y * 128;
  const int wid = t >> 6, lane = t & 63;
  const int wm = (wid & 1) * 64, wc = (wid >> 1) * 64;
  const int lm = lane & 15, q = lane >> 4;
  const int sr = t >> 1;        // staging row 0..127
  const int sc = (t & 1) * 32;  // staging k-offset: [sc, sc+32)
  if (t < 128) ush[t] = u_g[m0 + t];

  float4v acc[4][4];
#pragma unroll
  for (int i = 0; i < 4; ++i)
#pragma unroll
    for (int j = 0; j < 4; ++j) acc[i][j] = (float4v){0.f, 0.f, 0.f, 0.f};

  for (int seg = 0; seg < 3; ++seg) {
    const ushort* Ag = (seg == 1) ? El : Eh;
    const ushort* Xg = (seg == 2) ? XTl : XTh;
    for (int k0 = 0; k0 < 1024; k0 += 64) {
      __syncthreads();
      const ushort* ag = Ag + (size_t)(m0 + sr) * 1024 + k0 + sc;
      const ushort* xg = Xg + (size_t)(c0 + sr) * 1024 + k0 + sc;
      uint4 a0 = *(const uint4*)(ag);
      uint4 a1 = *(const uint4*)(ag + 8);
      uint4 a2 = *(const uint4*)(ag + 16);
      uint4 a3 = *(const uint4*)(ag + 24);
      uint4 x0 = *(const uint4*)(xg);
      uint4 x1 = *(const uint4*)(xg + 8);
      uint4 x2 = *(const uint4*)(xg + 16);
      uint4 x3 = *(const uint4*)(xg + 24);
      *(uint4*)&As[sr * LSTR + sc] = a0;
      *(uint4*)&As[sr * LSTR + sc + 8] = a1;
      *(uint4*)&As[sr * LSTR + sc + 16] = a2;
      *(uint4*)&As[sr * LSTR + sc + 24] = a3;
      *(uint4*)&Xs[sr * LSTR + sc] = x0;
      *(uint4*)&Xs[sr * LSTR + sc + 8] = x1;
      *(uint4*)&Xs[sr * LSTR + sc + 16] = x2;
      *(uint4*)&Xs[sr * LSTR + sc + 24] = x3;
      __syncthreads();
#pragma unroll
      for (int kk = 0; kk < 2; ++kk) {
        short8 af[4], xf[4];
#pragma unroll
        for (int i = 0; i < 4; ++i)
          af[i] = *(const short8*)&As[(wm + 16 * i + lm) * LSTR + kk * 32 +
                                      q * 8];
#pragma unroll
        for (int j = 0; j < 4; ++j)
          xf[j] = *(const short8*)&Xs[(wc + 16 * j + lm) * LSTR + kk * 32 +
                                      q * 8];
#pragma unroll
        for (int i = 0; i < 4; ++i)
#pragma unroll
          for (int j = 0; j < 4; ++j)
            acc[i][j] = __builtin_amdgcn_mfma_f32_16x16x32_bf16(
                af[i], xf[j], acc[i][j], 0, 0, 0);
      }
    }
  }
  // epilogue: D row = q*4 + reg, col = lm (m89-verified); scale by u_m
#pragma unroll
  for (int i = 0; i < 4; ++i) {
#pragma unroll
    for (int j = 0; j < 4; ++j) {
      const int ml = wm + 16 * i + q * 4;
      const int m = m0 + ml;
      const int c = c0 + wc + 16 * j + lm;
      const int bb = c >> 6, o = c & 63;
      float* dst = out + (size_t)bb * 65536 + (size_t)m * 64 + o;
#pragma unroll
      for (int r = 0; r < 4; ++r) dst[64 * r] = acc[i][j][r] * ush[ml + r];
    }
  }
}

// ---------------- kernel 3 (fp32 fallback): out = u ⊙ (E0·(v⊙XL)) ------------
__global__ __launch_bounds__(256) void k_gemm(const float* __restrict__ E0,
                                              const float* __restrict__ XL,
                                              const float* __restrict__ u_g,
                                              const float* __restrict__ v_g,
                                              float* __restrict__ out) {
  __shared__ float Asm[32][132];
  __shared__ float Xsm[32][132];
  const int t = threadIdx.x;
  const int m0 = blockIdx.x * 128;
  const int c0 = blockIdx.y * 128;
  const int my8 = (t >> 4) * 8;
  const int cx8 = (t & 15) * 8;
  const int kk = t & 31;
  const int rr = t >> 5;
  float acc[8][8] = {};

  for (int k0 = 0; k0 < 1024; k0 += 32) {
#pragma unroll
    for (int s = 0; s < 16; ++s)
      Asm[kk][rr + 8 * s] = E0[(size_t)(m0 + rr + 8 * s) * 1024 + k0 + kk];
#pragma unroll
    for (int s = 0; s < 4; ++s) {
      const int krow = k0 + rr + 8 * s;
      float vk = v_g[krow];
      float4 f = *(const float4*)&XL[(size_t)krow * 4096 + c0 + kk * 4];
      f.x *= vk;
      f.y *= vk;
      f.z *= vk;
      f.w *= vk;
      *(float4*)&Xsm[rr + 8 * s][kk * 4] = f;
    }
    __syncthreads();
#pragma unroll
    for (int k = 0; k < 32; ++k) {
      float a[8], xv[8];
      *(float4*)&a[0] = *(const float4*)&Asm[k][my8];
      *(float4*)&a[4] = *(const float4*)&Asm[k][my8 + 4];
      *(float4*)&xv[0] = *(const float4*)&Xsm[k][cx8];
      *(float4*)&xv[4] = *(const float4*)&Xsm[k][cx8 + 4];
#pragma unroll
      for (int i = 0; i < 8; ++i)
#pragma unroll
        for (int j = 0; j < 8; ++j) acc[i][j] += a[i] * xv[j];
    }
    __syncthreads();
  }

#pragma unroll
  for (int i = 0; i < 8; ++i) {
    const int m = m0 + my8 + i;
    const float um = u_g[m];
    const int c = c0 + cx8;
    const int bb = c >> 6, o = c & 63;
    float* dst = out + (size_t)bb * 65536 + (size_t)m * 64 + o;
#pragma unroll
    for (int j = 0; j < 8; ++j) dst[j] = acc[i][j] * um;
  }
}

// ---------------- launcher ---------------------------------------------------
extern "C" void kernel_launch(void* const* d_in, const int* in_sizes, int n_in,
                              void* d_out, int out_size, void* d_ws,
                              size_t ws_size, hipStream_t stream) {
  (void)in_sizes;
  (void)n_in;
  (void)out_size;
  const float* x = (const float*)d_in[0];
  const float* Alog = (const float*)d_in[1];
  const float* W1 = (const float*)d_in[2];
  const float* WV = (const float*)d_in[3];
  float* out = (float*)d_out;

  char* ws = (char*)d_ws;
  const size_t MB = 1024 * 1024;
  const size_t KB = 1024;
  const bool use_bf16 = ws_size >= (40 * MB + 256 * KB);

  float* E0;
  float* XL;
  float* P;
  float* u_g;
  float* v_g;
  unsigned* ctrl;
  __hip_bfloat16 *Eh = nullptr, *El = nullptr, *XTh = nullptr, *XTl = nullptr;
  if (use_bf16) {
    E0 = (float*)(ws);                      // 4 MB (unused in bf16 path)
    XL = (float*)(ws + 4 * MB);             // 16 MB
    Eh = (__hip_bfloat16*)(ws + 20 * MB);   // 2 MB
    El = (__hip_bfloat16*)(ws + 22 * MB);   // 2 MB
    XTh = (__hip_bfloat16*)(ws + 24 * MB);  // 8 MB
    XTl = (__hip_bfloat16*)(ws + 32 * MB);  // 8 MB -> 40 MB
    P = (float*)(ws + 40 * MB);             // 2*16*4 KB = 128 KB
    u_g = (float*)(ws + 40 * MB + 128 * KB);      // 4 KB
    v_g = (float*)(ws + 40 * MB + 132 * KB);      // 4 KB
    ctrl = (unsigned*)(ws + 40 * MB + 136 * KB);  // 4 KB
  } else {
    E0 = (float*)(ws);           // 4 MB
    XL = (float*)(ws + 4 * MB);  // 16 MB
    P = (float*)(ws + 20 * MB);  // 128 KB
    u_g = (float*)(ws + 20 * MB + 128 * KB);
    v_g = (float*)(ws + 20 * MB + 132 * KB);
    ctrl = (unsigned*)(ws + 20 * MB + 136 * KB);
  }

  hipMemsetAsync(ctrl, 0, 4096, stream);
  hipLaunchKernelGGL(k_front, dim3(256), dim3(1024), 0, stream, x, Alog, W1,
                     WV, E0, Eh, El, P, ctrl, u_g, v_g, XL, use_bf16 ? 1 : 0);
  if (use_bf16) {
    hipLaunchKernelGGL(k_xt, dim3(16, 64), dim3(256), 0, stream, XL, v_g, XTh,
                       XTl);
    hipLaunchKernelGGL(k_gemm3, dim3(8, 32), dim3(256), 0, stream,
                       (const ushort*)Eh, (const ushort*)El, (const ushort*)XTh,
                       (const ushort*)XTl, u_g, out);
  } else {
    hipLaunchKernelGGL(k_gemm, dim3(8, 32), dim3(256), 0, stream, E0, XL, u_g,
                       v_g, out);
  }
}